// Round 17
// baseline (28.561 us; speedup 1.0000x reference)
//
#include <hip/hip_runtime.h>
#include <stdint.h>

typedef __attribute__((ext_vector_type(8))) short short8;
typedef __attribute__((ext_vector_type(4))) float f32x4;

#define DEVI __device__ __forceinline__

DEVI ushort f2bf(float f) {
  union { float f; uint32_t u; } v; v.f = f;
  uint32_t r = v.u + 0x7fffu + ((v.u >> 16) & 1u);
  return (ushort)(r >> 16);
}

// HW packed f32->bf16 (RTNE, identical rounding to f2bf): 1 inst per 2 elems.
DEVI uint32_t cvtpk(float lo, float hi) {
  uint32_t r;
  asm("v_cvt_pk_bf16_f32 %0, %1, %2" : "=v"(r) : "v"(lo), "v"(hi));
  return r;
}
DEVI uint2 pack4(float a, float b, float c, float d) {
  uint2 o; o.x = cvtpk(a, b); o.y = cvtpk(c, d);
  return o;
}

// ---------------------------------------------------------------------------
// Quantum sim collapses analytically (params provably dead):
//   feats per 2x2 patch (v0,v1,v2,v3) = [cos v0, cos v1, cos v0*cos v2,
//   cos v1*cos v3]; CNOT chains = linear bit map; RZ phases cancel in |.|^2.
//
// Kernel 1: h1 = relu(feats(x) @ W1^T + b1). R17 = R12/R16 champion geometry
// (BM=BN=64, BK=64, 512 blocks x 512 threads, 8 waves, dbuf LDS) with a
// 2-DEEP register prefetch: two named stage sets S0/S1, explicitly x2
// unrolled K-loop (static buf/set indices). Each global load now gets
// ~1.5-2 phases (~600-800cyc) before its writeT vmcnt-drain, vs ~1 mma
// (~300cyc) in the 1-deep champion — the stall R7 targeted but confounded.
// ---------------------------------------------------------------------------
struct Stage1 {
  float2 atop[2], abot[2];   // x: 2 rows, 1 patch
  float4 bw[2];              // W1: 2 rows, 4 cols
};

__global__ __launch_bounds__(512) void gemm1_fused(
    const float* __restrict__ x, const float* __restrict__ W1,
    const float* __restrict__ b1, ushort* __restrict__ h1) {
  constexpr int LDA = 72;   // 144B row stride -> <=2-way b128 reads (free)
  constexpr int NK = 13;    // K = 832 (784 + pad)
  __shared__ ushort As[2][64 * LDA];   // 18432 B
  __shared__ ushort Bs[2][64 * LDA];   // 18432 B  (36864 total)

  const int tid = threadIdx.x;
  const int lane = tid & 63;
  const int w = tid >> 6;              // 8 waves: wm in {0,1}, wn in {0..3}
  const int wm = w >> 2, wn = w & 3;
  const int bm = blockIdx.x & 127, bn = blockIdx.x >> 7;
  const int m0 = bm * 64, n0 = bn * 64;

  const int srow = tid >> 4;        // 0..31: staging row within 32-row group
  const int pl = tid & 15;          // patch slot / float4 slot
  const int kc4 = pl * 4;

  f32x4 acc[2];                     // wave tile 32 x 16 (MF=2, NF=1)
#pragma unroll
  for (int m = 0; m < 2; ++m) {
    f32x4 z = {0.f, 0.f, 0.f, 0.f};
    acc[m] = z;
  }

  auto loadT = [&](Stage1& S, int kt) {
    const int q = kt * 16 + pl;                 // patch index
    if (q < 196) {
      const int i = q / 14, j = q - i * 14;
      const float* px = x + i * 56 + j * 2;
#pragma unroll
      for (int c = 0; c < 2; ++c) {
        const float* p = px + (size_t)(m0 + c * 32 + srow) * 784;
        S.atop[c] = *(const float2*)p;
        S.abot[c] = *(const float2*)(p + 28);
      }
    }
    const int k0 = kt * 64;
    if (k0 + kc4 < 784) {
#pragma unroll
      for (int c = 0; c < 2; ++c)
        S.bw[c] = *(const float4*)(W1 + (size_t)(n0 + c * 32 + srow) * 784 + k0 + kc4);
    } else {
#pragma unroll
      for (int c = 0; c < 2; ++c) S.bw[c] = make_float4(0.f, 0.f, 0.f, 0.f);
    }
  };

  auto writeT = [&](int buf, const Stage1& S, int kt) {
    const int q = kt * 16 + pl;
    ushort* as = As[buf];
    ushort* bs = Bs[buf];
    if (q < 196) {
#pragma unroll
      for (int c = 0; c < 2; ++c) {
        float c0 = __cosf(S.atop[c].x), c1 = __cosf(S.atop[c].y);
        float c2 = __cosf(S.abot[c].x), c3 = __cosf(S.abot[c].y);
        *(uint2*)(as + (c * 32 + srow) * LDA + pl * 4) =
            pack4(c0, c1, c0 * c2, c1 * c3);
      }
    } else {
      uint2 z; z.x = 0; z.y = 0;
#pragma unroll
      for (int c = 0; c < 2; ++c)
        *(uint2*)(as + (c * 32 + srow) * LDA + pl * 4) = z;
    }
#pragma unroll
    for (int c = 0; c < 2; ++c)
      *(uint2*)(bs + (c * 32 + srow) * LDA + kc4) =
          pack4(S.bw[c].x, S.bw[c].y, S.bw[c].z, S.bw[c].w);
  };

  auto mma = [&](int buf) {
    const ushort* as = As[buf];
    const ushort* bs = Bs[buf];
#pragma unroll
    for (int ks = 0; ks < 2; ++ks) {
      short8 af[2];
#pragma unroll
      for (int m = 0; m < 2; ++m) {
        int r = wm * 32 + m * 16 + (lane & 15);
        af[m] = *(const short8*)(as + r * LDA + ks * 32 + (lane >> 4) * 8);
      }
      int cdx = wn * 16 + (lane & 15);
      short8 bf = *(const short8*)(bs + cdx * LDA + ks * 32 + (lane >> 4) * 8);
#pragma unroll
      for (int m = 0; m < 2; ++m)
        acc[m] = __builtin_amdgcn_mfma_f32_16x16x32_bf16(af[m], bf, acc[m], 0, 0, 0);
    }
  };

  // prologue: S0=tile0, S1=tile1; tile0 -> buf0
  Stage1 S0, S1;
  loadT(S0, 0);
  loadT(S1, 1);
  writeT(0, S0, 0);
  __syncthreads();

  // 13 K-steps, x2 unrolled: even tiles in buf0, odd tiles in buf1.
  for (int kt = 0; kt < NK; kt += 2) {
    // even half: compute tile kt (buf0)
    if (kt + 2 < NK) loadT(S0, kt + 2);      // S0's tile kt was written
    mma(0);
    if (kt + 1 < NK) writeT(1, S1, kt + 1);  // S1 loaded ~2 phases ago
    __syncthreads();
    if (kt + 1 < NK) {
      // odd half: compute tile kt+1 (buf1)
      if (kt + 3 < NK) loadT(S1, kt + 3);
      mma(1);
      if (kt + 2 < NK) writeT(0, S0, kt + 2);
      __syncthreads();
    }
  }

  // C/D layout: col = lane&15, row = (lane>>4)*4 + reg   [m89-verified]
#pragma unroll
  for (int m = 0; m < 2; ++m) {
    const int colg = n0 + wn * 16 + (lane & 15);
    const float bval = b1[colg];
#pragma unroll
    for (int r = 0; r < 4; ++r) {
      const int rowg = m0 + wm * 32 + m * 16 + (lane >> 4) * 4 + r;
      h1[(size_t)rowg * 256 + colg] = f2bf(fmaxf(acc[m][r] + bval, 0.f));
    }
  }
}

// ---------------------------------------------------------------------------
// Kernel 2 (R16 champion, byte-identical): h2 = relu(h1 @ W2^T + b2) -> LDS;
// logits = h2 @ W3^T + b3, log_softmax. Grid 256 x 512 threads (8 waves,
// 2x4), BM=32/BN=128, K=256 in 4 dbuf steps.
// ---------------------------------------------------------------------------
__global__ __launch_bounds__(512) void gemm2_head(
    const ushort* __restrict__ h1, const float* __restrict__ W2,
    const float* __restrict__ b2, const float* __restrict__ W3,
    const float* __restrict__ b3, float* __restrict__ out) {
  constexpr int LDA = 72;
  constexpr int NK = 4;   // K = 256, BK = 64
  __shared__ ushort As[2][32 * LDA];    //  9216 B
  __shared__ ushort Bs[2][128 * LDA];   // 36864 B
  __shared__ float h2f[32][132];        // 16896 B
  __shared__ float W3s[1280];           //  5120 B  (68096 total, 2 blk/CU)

  const int tid = threadIdx.x;
  const int lane = tid & 63;
  const int w = tid >> 6;               // 8 waves: 2 (rows) x 4 (cols)
  const int wm = w >> 2, wn = w & 3;
  const int m0 = blockIdx.x * 32;

  for (int i = tid; i < 1280; i += 512) W3s[i] = W3[i];

  const bool ldA = tid < 256;
  const int ar = tid >> 3, asl = tid & 7;   // A: 32 rows x 8 uint4 slots

  uint4 av;
  float4 bw[4];                             // B: 128 rows x 16 f4 slots, 4/thr

  auto loadT = [&](int kt) {
    const int k0 = kt * 64;
    if (ldA) av = *(const uint4*)(h1 + (size_t)(m0 + ar) * 256 + k0 + asl * 8);
#pragma unroll
    for (int c = 0; c < 4; ++c) {
      const int flat = c * 512 + tid, r = flat >> 4, sl = flat & 15;
      bw[c] = *(const float4*)(W2 + (size_t)r * 256 + k0 + sl * 4);
    }
  };
  auto writeT = [&](int buf) {
    if (ldA) *(uint4*)(As[buf] + ar * LDA + asl * 8) = av;
#pragma unroll
    for (int c = 0; c < 4; ++c) {
      const int flat = c * 512 + tid, r = flat >> 4, sl = flat & 15;
      *(uint2*)(Bs[buf] + r * LDA + sl * 4) =
          pack4(bw[c].x, bw[c].y, bw[c].z, bw[c].w);
    }
  };

  f32x4 acc[2];                 // wave tile 16 x 32: rows wm*16, cols wn*32
#pragma unroll
  for (int n = 0; n < 2; ++n) {
    f32x4 z = {0.f, 0.f, 0.f, 0.f};
    acc[n] = z;
  }

  auto mma = [&](int buf) {
#pragma unroll
    for (int ks = 0; ks < 2; ++ks) {
      const int r = wm * 16 + (lane & 15);
      short8 af = *(const short8*)(As[buf] + r * LDA + ks * 32 + (lane >> 4) * 8);
#pragma unroll
      for (int n = 0; n < 2; ++n) {
        const int cdx = wn * 32 + n * 16 + (lane & 15);
        short8 bf = *(const short8*)(Bs[buf] + cdx * LDA + ks * 32 + (lane >> 4) * 8);
        acc[n] = __builtin_amdgcn_mfma_f32_16x16x32_bf16(af, bf, acc[n], 0, 0, 0);
      }
    }
  };

  loadT(0);
  writeT(0);
  __syncthreads();
  int cur = 0;
#pragma unroll
  for (int kt = 0; kt < NK; ++kt) {
    if (kt + 1 < NK) loadT(kt + 1);
    mma(cur);
    if (kt + 1 < NK) writeT(cur ^ 1);
    __syncthreads();
    cur ^= 1;
  }

  // h2 tile -> LDS f32 (bias + relu)
#pragma unroll
  for (int n = 0; n < 2; ++n) {
    const int col = wn * 32 + n * 16 + (lane & 15);
    const float bval = b2[col];
#pragma unroll
    for (int r = 0; r < 4; ++r)
      h2f[wm * 16 + (lane >> 4) * 4 + r][col] = fmaxf(acc[n][r] + bval, 0.f);
  }
  __syncthreads();

  // head: 32 rows x 16 partials; k = e*16 + p (8 iters); 4-level shfl reduce
  {
    const int r = tid >> 4, p = tid & 15;
    float a10[10];
#pragma unroll
    for (int n = 0; n < 10; ++n) a10[n] = 0.f;
#pragma unroll
    for (int e = 0; e < 8; ++e) {
      const int k = e * 16 + p;
      const float hv = h2f[r][k];
#pragma unroll
      for (int n = 0; n < 10; ++n) a10[n] = fmaf(hv, W3s[n * 128 + k], a10[n]);
    }
#pragma unroll
    for (int n = 0; n < 10; ++n) {
      a10[n] += __shfl_xor(a10[n], 1);
      a10[n] += __shfl_xor(a10[n], 2);
      a10[n] += __shfl_xor(a10[n], 4);
      a10[n] += __shfl_xor(a10[n], 8);
    }
    if (p == 0) {
#pragma unroll
      for (int n = 0; n < 10; ++n) a10[n] += b3[n];
      float mx = a10[0];
#pragma unroll
      for (int n = 1; n < 10; ++n) mx = fmaxf(mx, a10[n]);
      float s = 0.f;
#pragma unroll
      for (int n = 0; n < 10; ++n) s += __expf(a10[n] - mx);
      const float lse = mx + __logf(s);
      float* po = out + (size_t)(m0 + r) * 10;
#pragma unroll
      for (int n = 0; n < 10; ++n) po[n] = a10[n] - lse;
    }
  }
}

// ---------------------------------------------------------------------------
extern "C" void kernel_launch(void* const* d_in, const int* in_sizes, int n_in,
                              void* d_out, int out_size, void* d_ws, size_t ws_size,
                              hipStream_t stream) {
  const float* x  = (const float*)d_in[0];   // (8192,1,28,28)
  // d_in[1] = params: provably unused (diagonal phases cancel in |amp|^2)
  const float* W1 = (const float*)d_in[2];
  const float* b1 = (const float*)d_in[3];
  const float* W2 = (const float*)d_in[4];
  const float* b2 = (const float*)d_in[5];
  const float* W3 = (const float*)d_in[6];
  const float* b3 = (const float*)d_in[7];
  float* out = (float*)d_out;

  ushort* h1 = (ushort*)d_ws;                 // 8192 x 256 bf16 (4.2 MB)

  hipLaunchKernelGGL(gemm1_fused, dim3(512), dim3(512), 0, stream, x, W1, b1, h1);
  hipLaunchKernelGGL(gemm2_head, dim3(256), dim3(512), 0, stream, h1, W2, b2, W3, b3, out);
}

// Round 18
// 27.501 us; speedup vs baseline: 1.0385x; 1.0385x over previous
//
#include <hip/hip_runtime.h>
#include <stdint.h>

typedef __attribute__((ext_vector_type(8))) short short8;
typedef __attribute__((ext_vector_type(4))) float f32x4;

#define DEVI __device__ __forceinline__

DEVI ushort f2bf(float f) {
  union { float f; uint32_t u; } v; v.f = f;
  uint32_t r = v.u + 0x7fffu + ((v.u >> 16) & 1u);
  return (ushort)(r >> 16);
}

// HW packed f32->bf16 (RTNE, identical rounding to f2bf): 1 inst per 2 elems.
DEVI uint32_t cvtpk(float lo, float hi) {
  uint32_t r;
  asm("v_cvt_pk_bf16_f32 %0, %1, %2" : "=v"(r) : "v"(lo), "v"(hi));
  return r;
}
DEVI uint2 pack4(float a, float b, float c, float d) {
  uint2 o; o.x = cvtpk(a, b); o.y = cvtpk(c, d);
  return o;
}

// ---------------------------------------------------------------------------
// Quantum sim collapses analytically (params provably dead):
//   feats per 2x2 patch (v0,v1,v2,v3) = [cos v0, cos v1, cos v0*cos v2,
//   cos v1*cos v3]; CNOT chains = linear bit map; RZ phases cancel in |.|^2.
//
// Kernel 1: h1 = relu(feats(x) @ W1^T + b1). R18 = R16 champion with
// VECTORIZED A-staging: since patch pairs (q, q+1) with q even never
// straddle a patch row (q even -> j even <= 12), one thread owns 2 adjacent
// patches of 1 batch row: 2x float4 x-loads (16B aligned, vs 4x float2) and
// 1x ds_write_b128 (vs 2x ds_write_b64). Same cos count; ~3 fewer issue
// slots per thread per K-step on the staging critical path.
// BM=BN=64, BK=64, dbuf, 512 blocks x 512 threads (8 waves) = 4 waves/SIMD.
// ---------------------------------------------------------------------------
__global__ __launch_bounds__(512) void gemm1_fused(
    const float* __restrict__ x, const float* __restrict__ W1,
    const float* __restrict__ b1, ushort* __restrict__ h1) {
  constexpr int LDA = 72;   // 144B row stride -> <=2-way b128 reads (free)
  constexpr int NK = 13;    // K = 832 (784 + pad)
  __shared__ ushort As[2][64 * LDA];   // 18432 B
  __shared__ ushort Bs[2][64 * LDA];   // 18432 B  (36864 total)

  const int tid = threadIdx.x;
  const int lane = tid & 63;
  const int w = tid >> 6;              // 8 waves: wm in {0,1}, wn in {0..3}
  const int wm = w >> 2, wn = w & 3;
  const int bm = blockIdx.x & 127, bn = blockIdx.x >> 7;
  const int m0 = bm * 64, n0 = bn * 64;

  // A-staging: 64 rows x 8 patch-pairs (1 row, 2 adjacent patches / thread)
  const int arow = tid >> 3, pl2 = tid & 7;
  // B-staging: 2 x 32 rows x 16 float4 slots
  const int srow = tid >> 4;           // 0..31
  const int kc4 = (tid & 15) * 4;

  float4 atop, abot;                   // 2 patches of x (4 top + 4 bot pix)
  float4 bw[2];                        // W1: 2 rows, 4 cols

  f32x4 acc[2];                        // wave tile 32 x 16 (MF=2, NF=1)
#pragma unroll
  for (int m = 0; m < 2; ++m) {
    f32x4 z = {0.f, 0.f, 0.f, 0.f};
    acc[m] = z;
  }

  auto loadT = [&](int kt) {
    const int q0 = kt * 16 + pl2 * 2;          // even patch index
    if (q0 < 196) {
      const int i = q0 / 14, j0 = q0 - i * 14; // j0 even <= 12: pair in-row
      const float* p = x + (size_t)(m0 + arow) * 784 + i * 56 + j0 * 2;
      atop = *(const float4*)p;                // 16B aligned
      abot = *(const float4*)(p + 28);
    }
    const int k0 = kt * 64;
    if (k0 + kc4 < 784) {
#pragma unroll
      for (int c = 0; c < 2; ++c)
        bw[c] = *(const float4*)(W1 + (size_t)(n0 + c * 32 + srow) * 784 + k0 + kc4);
    } else {
#pragma unroll
      for (int c = 0; c < 2; ++c) bw[c] = make_float4(0.f, 0.f, 0.f, 0.f);
    }
  };

  auto writeT = [&](int buf, int kt) {
    const int q0 = kt * 16 + pl2 * 2;
    ushort* as = As[buf];
    ushort* bs = Bs[buf];
    uint4 av;
    if (q0 < 196) {
      float t0 = __cosf(atop.x), t1 = __cosf(atop.y);
      float t2 = __cosf(atop.z), t3 = __cosf(atop.w);
      float b0 = __cosf(abot.x), b1c = __cosf(abot.y);
      float b2 = __cosf(abot.z), b3c = __cosf(abot.w);
      av.x = cvtpk(t0, t1);            // patch 0: [c0, c1, c0*c2, c1*c3]
      av.y = cvtpk(t0 * b0, t1 * b1c);
      av.z = cvtpk(t2, t3);            // patch 1
      av.w = cvtpk(t2 * b2, t3 * b3c);
    } else {
      av.x = 0; av.y = 0; av.z = 0; av.w = 0;
    }
    *(uint4*)(as + arow * LDA + pl2 * 8) = av;   // one ds_write_b128
#pragma unroll
    for (int c = 0; c < 2; ++c)
      *(uint2*)(bs + (c * 32 + srow) * LDA + kc4) =
          pack4(bw[c].x, bw[c].y, bw[c].z, bw[c].w);
  };

  auto mma = [&](int buf) {
    const ushort* as = As[buf];
    const ushort* bs = Bs[buf];
#pragma unroll
    for (int ks = 0; ks < 2; ++ks) {
      short8 af[2];
#pragma unroll
      for (int m = 0; m < 2; ++m) {
        int r = wm * 32 + m * 16 + (lane & 15);
        af[m] = *(const short8*)(as + r * LDA + ks * 32 + (lane >> 4) * 8);
      }
      int cdx = wn * 16 + (lane & 15);
      short8 bf = *(const short8*)(bs + cdx * LDA + ks * 32 + (lane >> 4) * 8);
#pragma unroll
      for (int m = 0; m < 2; ++m)
        acc[m] = __builtin_amdgcn_mfma_f32_16x16x32_bf16(af[m], bf, acc[m], 0, 0, 0);
    }
  };

  loadT(0);
  writeT(0, 0);
  __syncthreads();
  int cur = 0;
  for (int kt = 0; kt < NK; ++kt) {
    if (kt + 1 < NK) loadT(kt + 1);
    mma(cur);
    if (kt + 1 < NK) writeT(cur ^ 1, kt + 1);
    __syncthreads();
    cur ^= 1;
  }

  // C/D layout: col = lane&15, row = (lane>>4)*4 + reg   [m89-verified]
#pragma unroll
  for (int m = 0; m < 2; ++m) {
    const int colg = n0 + wn * 16 + (lane & 15);
    const float bval = b1[colg];
#pragma unroll
    for (int r = 0; r < 4; ++r) {
      const int rowg = m0 + wm * 32 + m * 16 + (lane >> 4) * 4 + r;
      h1[(size_t)rowg * 256 + colg] = f2bf(fmaxf(acc[m][r] + bval, 0.f));
    }
  }
}

// ---------------------------------------------------------------------------
// Kernel 2 (R16 champion, byte-identical): h2 = relu(h1 @ W2^T + b2) -> LDS;
// logits = h2 @ W3^T + b3, log_softmax. Grid 256 x 512 threads (8 waves,
// 2x4), BM=32/BN=128, K=256 in 4 dbuf steps.
// ---------------------------------------------------------------------------
__global__ __launch_bounds__(512) void gemm2_head(
    const ushort* __restrict__ h1, const float* __restrict__ W2,
    const float* __restrict__ b2, const float* __restrict__ W3,
    const float* __restrict__ b3, float* __restrict__ out) {
  constexpr int LDA = 72;
  constexpr int NK = 4;   // K = 256, BK = 64
  __shared__ ushort As[2][32 * LDA];    //  9216 B
  __shared__ ushort Bs[2][128 * LDA];   // 36864 B
  __shared__ float h2f[32][132];        // 16896 B
  __shared__ float W3s[1280];           //  5120 B  (68096 total, 2 blk/CU)

  const int tid = threadIdx.x;
  const int lane = tid & 63;
  const int w = tid >> 6;               // 8 waves: 2 (rows) x 4 (cols)
  const int wm = w >> 2, wn = w & 3;
  const int m0 = blockIdx.x * 32;

  for (int i = tid; i < 1280; i += 512) W3s[i] = W3[i];

  const bool ldA = tid < 256;
  const int ar = tid >> 3, asl = tid & 7;   // A: 32 rows x 8 uint4 slots

  uint4 av;
  float4 bw[4];                             // B: 128 rows x 16 f4 slots, 4/thr

  auto loadT = [&](int kt) {
    const int k0 = kt * 64;
    if (ldA) av = *(const uint4*)(h1 + (size_t)(m0 + ar) * 256 + k0 + asl * 8);
#pragma unroll
    for (int c = 0; c < 4; ++c) {
      const int flat = c * 512 + tid, r = flat >> 4, sl = flat & 15;
      bw[c] = *(const float4*)(W2 + (size_t)r * 256 + k0 + sl * 4);
    }
  };
  auto writeT = [&](int buf) {
    if (ldA) *(uint4*)(As[buf] + ar * LDA + asl * 8) = av;
#pragma unroll
    for (int c = 0; c < 4; ++c) {
      const int flat = c * 512 + tid, r = flat >> 4, sl = flat & 15;
      *(uint2*)(Bs[buf] + r * LDA + sl * 4) =
          pack4(bw[c].x, bw[c].y, bw[c].z, bw[c].w);
    }
  };

  f32x4 acc[2];                 // wave tile 16 x 32: rows wm*16, cols wn*32
#pragma unroll
  for (int n = 0; n < 2; ++n) {
    f32x4 z = {0.f, 0.f, 0.f, 0.f};
    acc[n] = z;
  }

  auto mma = [&](int buf) {
#pragma unroll
    for (int ks = 0; ks < 2; ++ks) {
      const int r = wm * 16 + (lane & 15);
      short8 af = *(const short8*)(As[buf] + r * LDA + ks * 32 + (lane >> 4) * 8);
#pragma unroll
      for (int n = 0; n < 2; ++n) {
        const int cdx = wn * 32 + n * 16 + (lane & 15);
        short8 bf = *(const short8*)(Bs[buf] + cdx * LDA + ks * 32 + (lane >> 4) * 8);
        acc[n] = __builtin_amdgcn_mfma_f32_16x16x32_bf16(af, bf, acc[n], 0, 0, 0);
      }
    }
  };

  loadT(0);
  writeT(0);
  __syncthreads();
  int cur = 0;
#pragma unroll
  for (int kt = 0; kt < NK; ++kt) {
    if (kt + 1 < NK) loadT(kt + 1);
    mma(cur);
    if (kt + 1 < NK) writeT(cur ^ 1);
    __syncthreads();
    cur ^= 1;
  }

  // h2 tile -> LDS f32 (bias + relu)
#pragma unroll
  for (int n = 0; n < 2; ++n) {
    const int col = wn * 32 + n * 16 + (lane & 15);
    const float bval = b2[col];
#pragma unroll
    for (int r = 0; r < 4; ++r)
      h2f[wm * 16 + (lane >> 4) * 4 + r][col] = fmaxf(acc[n][r] + bval, 0.f);
  }
  __syncthreads();

  // head: 32 rows x 16 partials; k = e*16 + p (8 iters); 4-level shfl reduce
  {
    const int r = tid >> 4, p = tid & 15;
    float a10[10];
#pragma unroll
    for (int n = 0; n < 10; ++n) a10[n] = 0.f;
#pragma unroll
    for (int e = 0; e < 8; ++e) {
      const int k = e * 16 + p;
      const float hv = h2f[r][k];
#pragma unroll
      for (int n = 0; n < 10; ++n) a10[n] = fmaf(hv, W3s[n * 128 + k], a10[n]);
    }
#pragma unroll
    for (int n = 0; n < 10; ++n) {
      a10[n] += __shfl_xor(a10[n], 1);
      a10[n] += __shfl_xor(a10[n], 2);
      a10[n] += __shfl_xor(a10[n], 4);
      a10[n] += __shfl_xor(a10[n], 8);
    }
    if (p == 0) {
#pragma unroll
      for (int n = 0; n < 10; ++n) a10[n] += b3[n];
      float mx = a10[0];
#pragma unroll
      for (int n = 1; n < 10; ++n) mx = fmaxf(mx, a10[n]);
      float s = 0.f;
#pragma unroll
      for (int n = 0; n < 10; ++n) s += __expf(a10[n] - mx);
      const float lse = mx + __logf(s);
      float* po = out + (size_t)(m0 + r) * 10;
#pragma unroll
      for (int n = 0; n < 10; ++n) po[n] = a10[n] - lse;
    }
  }
}

// ---------------------------------------------------------------------------
extern "C" void kernel_launch(void* const* d_in, const int* in_sizes, int n_in,
                              void* d_out, int out_size, void* d_ws, size_t ws_size,
                              hipStream_t stream) {
  const float* x  = (const float*)d_in[0];   // (8192,1,28,28)
  // d_in[1] = params: provably unused (diagonal phases cancel in |amp|^2)
  const float* W1 = (const float*)d_in[2];
  const float* b1 = (const float*)d_in[3];
  const float* W2 = (const float*)d_in[4];
  const float* b2 = (const float*)d_in[5];
  const float* W3 = (const float*)d_in[6];
  const float* b3 = (const float*)d_in[7];
  float* out = (float*)d_out;

  ushort* h1 = (ushort*)d_ws;                 // 8192 x 256 bf16 (4.2 MB)

  hipLaunchKernelGGL(gemm1_fused, dim3(512), dim3(512), 0, stream, x, W1, b1, h1);
  hipLaunchKernelGGL(gemm2_head, dim3(256), dim3(512), 0, stream, h1, W2, b2, W3, b3, out);
}